// Round 1
// baseline (47.888 us; speedup 1.0000x reference)
//
#include <hip/hip_runtime.h>
#include <hip/hip_bf16.h>

typedef __attribute__((ext_vector_type(8))) short short8;
typedef __attribute__((ext_vector_type(4))) float f32x4;

#define OUT_DIM 11008
#define IN_DIM  4096
#define B_DIM   32
#define NT      256   // output cols per block
#define KC      64    // k per staged chunk
#define KSPL    16    // k-split across blocks
#define KPB     (IN_DIM / KSPL)   // 256 k per block

__device__ __forceinline__ short f2bf(float f) {
  __hip_bfloat16 h = __float2bfloat16(f);
  return *reinterpret_cast<short*>(&h);
}

__global__ __launch_bounds__(256, 4)
void bitnet_mfma(const float* __restrict__ x,
                 const float* __restrict__ w,
                 const float* __restrict__ scale,
                 float* __restrict__ y)
{
  // bf16 tiles, XOR-swizzled: short-index k ^= (row&7)<<3  (== byte ^ (row&7)<<4)
  __shared__ short lw[NT * KC];     // 32 KB
  __shared__ short lx[B_DIM * KC];  // 4 KB

  const int tid   = threadIdx.x;
  const int obase = blockIdx.x * NT;
  const int k0    = blockIdx.y * KPB;

  const int lane = tid & 63;
  const int wv   = tid >> 6;   // wave 0..3 -> 64 output cols each
  const int l15  = lane & 15;
  const int lg   = lane >> 4;  // 0..3

  f32x4 acc[2][4];
#pragma unroll
  for (int m = 0; m < 2; ++m)
#pragma unroll
    for (int n = 0; n < 4; ++n)
      acc[m][n] = (f32x4){0.f, 0.f, 0.f, 0.f};

  const int xrow = tid >> 3;   // x staging: 32 rows x 8 octets = 256 threads
  const int xk8  = tid & 7;

  for (int kc = k0; kc < k0 + KPB; kc += KC) {
    // ---- stage W tile: NT x KC fp32 -> bf16, swizzled ----
#pragma unroll
    for (int it = 0; it < 8; ++it) {
      const int oct = it * 256 + tid;
      const int row = oct >> 3;
      const int k8  = oct & 7;
      const float* src = w + (size_t)(obase + row) * IN_DIM + kc + k8 * 8;
      f32x4 f0 = *reinterpret_cast<const f32x4*>(src);
      f32x4 f1 = *reinterpret_cast<const f32x4*>(src + 4);
      short8 v;
      v[0]=f2bf(f0[0]); v[1]=f2bf(f0[1]); v[2]=f2bf(f0[2]); v[3]=f2bf(f0[3]);
      v[4]=f2bf(f1[0]); v[5]=f2bf(f1[1]); v[6]=f2bf(f1[2]); v[7]=f2bf(f1[3]);
      const int sidx = row * KC + ((k8 * 8) ^ ((row & 7) << 3));
      *reinterpret_cast<short8*>(&lw[sidx]) = v;
    }
    // ---- stage x tile: 32 x KC ----
    {
      const float* src = x + (size_t)xrow * IN_DIM + kc + xk8 * 8;
      f32x4 f0 = *reinterpret_cast<const f32x4*>(src);
      f32x4 f1 = *reinterpret_cast<const f32x4*>(src + 4);
      short8 v;
      v[0]=f2bf(f0[0]); v[1]=f2bf(f0[1]); v[2]=f2bf(f0[2]); v[3]=f2bf(f0[3]);
      v[4]=f2bf(f1[0]); v[5]=f2bf(f1[1]); v[6]=f2bf(f1[2]); v[7]=f2bf(f1[3]);
      const int sidx = xrow * KC + ((xk8 * 8) ^ ((xrow & 7) << 3));
      *reinterpret_cast<short8*>(&lx[sidx]) = v;
    }
    __syncthreads();

    // ---- MFMA: 2 k-steps x (2 m-frags x 4 n-frags) ----
#pragma unroll
    for (int s = 0; s < 2; ++s) {
      short8 a[2], b[4];
#pragma unroll
      for (int m = 0; m < 2; ++m) {
        const int row = m * 16 + l15;
        const int kk  = s * 32 + lg * 8;
        a[m] = *reinterpret_cast<const short8*>(&lx[row * KC + (kk ^ ((row & 7) << 3))]);
      }
#pragma unroll
      for (int n = 0; n < 4; ++n) {
        const int row = wv * 64 + n * 16 + l15;
        const int kk  = s * 32 + lg * 8;
        b[n] = *reinterpret_cast<const short8*>(&lw[row * KC + (kk ^ ((row & 7) << 3))]);
      }
#pragma unroll
      for (int m = 0; m < 2; ++m)
#pragma unroll
        for (int n = 0; n < 4; ++n)
          acc[m][n] = __builtin_amdgcn_mfma_f32_16x16x32_bf16(a[m], b[n], acc[m][n], 0, 0, 0);
    }
    __syncthreads();
  }

  // ---- epilogue: scale + split-K combine via fp32 atomics ----
  const float s = scale[0];
#pragma unroll
  for (int m = 0; m < 2; ++m)
#pragma unroll
    for (int n = 0; n < 4; ++n)
#pragma unroll
      for (int r = 0; r < 4; ++r) {
        const int brow = m * 16 + lg * 4 + r;        // C/D: row=(lane>>4)*4+reg
        const int o    = obase + wv * 64 + n * 16 + l15;  // col=lane&15
        atomicAdd(&y[(size_t)brow * OUT_DIM + o], acc[m][n][r] * s);
      }
}

extern "C" void kernel_launch(void* const* d_in, const int* in_sizes, int n_in,
                              void* d_out, int out_size, void* d_ws, size_t ws_size,
                              hipStream_t stream) {
  const float* x = (const float*)d_in[0];
  const float* w = (const float*)d_in[1];
  const float* s = (const float*)d_in[2];
  float* y = (float*)d_out;
  // split-K accumulates with atomics; harness does not re-zero between replays
  hipMemsetAsync(y, 0, (size_t)out_size * sizeof(float), stream);
  dim3 grid(OUT_DIM / NT, KSPL);  // 43 x 16 = 688 blocks
  bitnet_mfma<<<grid, 256, 0, stream>>>(x, w, s, y);
}

// Round 2
// 47.109 us; speedup vs baseline: 1.0165x; 1.0165x over previous
//
#include <hip/hip_runtime.h>
#include <hip/hip_bf16.h>

typedef __attribute__((ext_vector_type(8))) short short8;
typedef __attribute__((ext_vector_type(4))) float f32x4;

#define OUT_DIM 11008
#define IN_DIM  4096
#define B_DIM   32
#define KSPL    16
#define KPB     (IN_DIM / KSPL)        // 256 k per split-K block
#define PART_ELEMS (B_DIM * OUT_DIM)   // 352256 floats per partial

__device__ __forceinline__ short8 cvt8(const float* __restrict__ src) {
  f32x4 f0 = *reinterpret_cast<const f32x4*>(src);
  f32x4 f1 = *reinterpret_cast<const f32x4*>(src + 4);
  short8 v;
  __hip_bfloat16 h;
  h = __float2bfloat16(f0[0]); v[0] = *reinterpret_cast<short*>(&h);
  h = __float2bfloat16(f0[1]); v[1] = *reinterpret_cast<short*>(&h);
  h = __float2bfloat16(f0[2]); v[2] = *reinterpret_cast<short*>(&h);
  h = __float2bfloat16(f0[3]); v[3] = *reinterpret_cast<short*>(&h);
  h = __float2bfloat16(f1[0]); v[4] = *reinterpret_cast<short*>(&h);
  h = __float2bfloat16(f1[1]); v[5] = *reinterpret_cast<short*>(&h);
  h = __float2bfloat16(f1[2]); v[6] = *reinterpret_cast<short*>(&h);
  h = __float2bfloat16(f1[3]); v[7] = *reinterpret_cast<short*>(&h);
  return v;
}

// No LDS, no barriers: each wave owns 64 output columns, loads its MFMA
// fragments directly from global (B: 16 rows x 128B, exactly one cache line
// per row per k-step), converts in-register, accumulates, stores a split-K
// partial to d_ws.
__global__ __launch_bounds__(256, 4)
void bitnet_partial(const float* __restrict__ x,
                    const float* __restrict__ w,
                    float* __restrict__ ws)
{
  const int tid  = threadIdx.x;
  const int lane = tid & 63;
  const int wv   = tid >> 6;       // wave 0..3
  const int l15  = lane & 15;
  const int lg   = lane >> 4;      // 0..3 -> k sub-group
  const int ow   = blockIdx.x * 256 + wv * 64;   // wave's output-col base
  const int k0   = blockIdx.y * KPB;

  f32x4 acc[2][4];
#pragma unroll
  for (int m = 0; m < 2; ++m)
#pragma unroll
    for (int n = 0; n < 4; ++n)
      acc[m][n] = (f32x4){0.f, 0.f, 0.f, 0.f};

  const float* wbase = w + (size_t)(ow + l15) * IN_DIM + k0 + lg * 8;
  const float* xbase = x + (size_t)l15 * IN_DIM + k0 + lg * 8;

#pragma unroll 2
  for (int t = 0; t < KPB / 32; ++t) {
    const int kk = t * 32;
    short8 aa[2], bb[4];
#pragma unroll
    for (int m = 0; m < 2; ++m)
      aa[m] = cvt8(xbase + (size_t)m * 16 * IN_DIM + kk);
#pragma unroll
    for (int n = 0; n < 4; ++n)
      bb[n] = cvt8(wbase + (size_t)n * 16 * IN_DIM + kk);
#pragma unroll
    for (int m = 0; m < 2; ++m)
#pragma unroll
      for (int n = 0; n < 4; ++n)
        acc[m][n] = __builtin_amdgcn_mfma_f32_16x16x32_bf16(aa[m], bb[n], acc[m][n], 0, 0, 0);
  }

  // partial store: ws[blockIdx.y][b][o], plain coalesced stores
  float* out = ws + (size_t)blockIdx.y * PART_ELEMS;
#pragma unroll
  for (int m = 0; m < 2; ++m)
#pragma unroll
    for (int n = 0; n < 4; ++n)
#pragma unroll
      for (int r = 0; r < 4; ++r) {
        const int brow = m * 16 + lg * 4 + r;   // C/D: row = (lane>>4)*4 + reg
        const int o    = ow + n * 16 + l15;     // col = lane&15
        out[(size_t)brow * OUT_DIM + o] = acc[m][n][r];
      }
}

// y[b][o] = scale * sum_{s<16} ws[s][b][o]; 344*256 threads x f32x4 each
__global__ __launch_bounds__(256)
void bitnet_reduce(const float* __restrict__ ws,
                   const float* __restrict__ scale,
                   float* __restrict__ y)
{
  const size_t base = ((size_t)blockIdx.x * 256 + threadIdx.x) * 4;
  f32x4 s = (f32x4){0.f, 0.f, 0.f, 0.f};
#pragma unroll
  for (int i = 0; i < KSPL; ++i) {
    f32x4 v = *reinterpret_cast<const f32x4*>(ws + (size_t)i * PART_ELEMS + base);
    s += v;
  }
  const float sc = scale[0];
  s *= sc;
  *reinterpret_cast<f32x4*>(y + base) = s;
}

extern "C" void kernel_launch(void* const* d_in, const int* in_sizes, int n_in,
                              void* d_out, int out_size, void* d_ws, size_t ws_size,
                              hipStream_t stream) {
  const float* x = (const float*)d_in[0];
  const float* w = (const float*)d_in[1];
  const float* s = (const float*)d_in[2];
  float* y  = (float*)d_out;
  float* ws = (float*)d_ws;   // needs KSPL*PART_ELEMS*4 = 22.5 MB

  dim3 grid(OUT_DIM / 256, KSPL);   // 43 x 16
  bitnet_partial<<<grid, 256, 0, stream>>>(x, w, ws);
  bitnet_reduce<<<PART_ELEMS / 1024, 256, 0, stream>>>(ws, s, y);
}